// Round 6
// baseline (6206.135 us; speedup 1.0000x reference)
//
#include <hip/hip_runtime.h>

#define N_NODES 100000
#define N_EDGES 1000000

// ---------------- zero: grid-stride float4 fill ----------------
__global__ __launch_bounds__(256) void zero_kernel(float4* __restrict__ p, long n4) {
  long i = (long)blockIdx.x * 256 + threadIdx.x;
  long stride = (long)gridDim.x * 256;
  float4 z = make_float4(0.f, 0.f, 0.f, 0.f);
  for (; i < n4; i += stride) p[i] = z;
}

// ---------------- encoder: h0 = relu(x @ enc_w + enc_b), x[N,32] w[32,128] ----------------
__global__ __launch_bounds__(256) void encoder_kernel(
    const float* __restrict__ x, const float* __restrict__ w,
    const float* __restrict__ b, float* __restrict__ h) {
  __shared__ float ws[32 * 128];
  __shared__ float xs[16 * 32];
  __shared__ float bs[128];
  int tid = threadIdx.x;
#pragma unroll
  for (int i = 0; i < 4; ++i)
    reinterpret_cast<float4*>(ws)[tid + i * 256] =
        reinterpret_cast<const float4*>(w)[tid + i * 256];
  if (tid < 128) bs[tid] = b[tid];
  int n0 = blockIdx.x * 16;
  if (tid < 128)
    reinterpret_cast<float4*>(xs)[tid] =
        reinterpret_cast<const float4*>(x + (size_t)n0 * 32)[tid];
  __syncthreads();
  int f = tid & 127;
  int ng = tid >> 7;  // 2 groups x 8 nodes
#pragma unroll
  for (int i = 0; i < 8; ++i) {
    int nl = ng * 8 + i;
    float acc = bs[f];
#pragma unroll
    for (int k = 0; k < 32; ++k) acc = fmaf(xs[nl * 32 + k], ws[k * 128 + f], acc);
    h[(size_t)(n0 + nl) * 128 + f] = fmaxf(acc, 0.f);
  }
}

// ---------------- degree: deg[dst] += 1 ----------------
__global__ __launch_bounds__(256) void deg_kernel(const int* __restrict__ ei,
                                                  float* __restrict__ deg) {
  int e = blockIdx.x * 256 + threadIdx.x;
  if (e < N_EDGES) atomicAdd(&deg[ei[N_EDGES + e]], 1.0f);
}

// ---------------- scatter: agg[dst, f] += h[src, f] * (ea @ e_w + e_b)[f] ----------------
// agg has row stride F
template <int F>
__global__ __launch_bounds__(256) void scatter_mul(
    const float* __restrict__ h, const float* __restrict__ edge_attr,
    const int* __restrict__ ei, const float* __restrict__ ew,
    const float* __restrict__ eb, float* __restrict__ agg) {
  constexpr int Q = F / 4;
  int gid = blockIdx.x * 256 + threadIdx.x;
  int e = gid / Q;
  int q = gid % Q;
  if (e >= N_EDGES) return;
  int f = q * 4;
  int s = ei[e];
  int d = ei[N_EDGES + e];
  float a0 = edge_attr[2 * e];
  float a1 = edge_attr[2 * e + 1];
  float4 w0 = *reinterpret_cast<const float4*>(&ew[f]);
  float4 w1 = *reinterpret_cast<const float4*>(&ew[F + f]);
  float4 bb = *reinterpret_cast<const float4*>(&eb[f]);
  float4 hv = *reinterpret_cast<const float4*>(&h[(size_t)s * F + f]);
  float m0 = hv.x * fmaf(a0, w0.x, fmaf(a1, w1.x, bb.x));
  float m1 = hv.y * fmaf(a0, w0.y, fmaf(a1, w1.y, bb.y));
  float m2 = hv.z * fmaf(a0, w0.z, fmaf(a1, w1.z, bb.z));
  float m3 = hv.w * fmaf(a0, w0.w, fmaf(a1, w1.w, bb.w));
  float* o = &agg[(size_t)d * F + f];
  atomicAdd(o + 0, m0);
  atomicAdd(o + 1, m1);
  atomicAdd(o + 2, m2);
  atomicAdd(o + 3, m3);
}

// ---------------- scale: agg[n, :] *= 1/max(deg[n],1) ----------------
template <int F>
__global__ __launch_bounds__(256) void scale_kernel(const float* __restrict__ deg,
                                                    float* __restrict__ agg) {
  constexpr int Q = F / 4;
  int gid = blockIdx.x * 256 + threadIdx.x;
  int n = gid / Q;
  int q = gid % Q;
  if (n >= N_NODES) return;
  float dinv = 1.f / fmaxf(deg[n], 1.f);
  float4* p = reinterpret_cast<float4*>(&agg[(size_t)n * F + q * 4]);
  float4 v = *p;
  v.x *= dinv; v.y *= dinv; v.z *= dinv; v.w *= dinv;
  *p = v;
}

// ---------------- two-operand GEMM: T = relu(A1 @ W[0:F] + A2 @ W[F:2F] + bias) ----------------
// If !FUSE_DEC: C = T  (C is [M,N])
// If FUSE_DEC:  out[m,0:2] += T[m, col0:col0+128] @ dw  (+ db once, from blockIdx.y==0)
// BM=BN=128, BK=16, 256 threads, 8x8 per thread
template <bool FUSE_DEC>
__global__ __launch_bounds__(256) void gemm2_bias_relu(
    const float* __restrict__ A1, const float* __restrict__ A2,
    const float* __restrict__ W, const float* __restrict__ bias,
    float* __restrict__ C,
    const float* __restrict__ dw, const float* __restrict__ db,
    float* __restrict__ out, int M, int F, int N) {
  constexpr int BM = 128, BN = 128, BK = 16, PAD = 4;
  __shared__ float As[BK][BM + PAD];  // transposed: As[k][m]
  __shared__ float Ws[BK][BN + PAD];
  int tid = threadIdx.x;
  int tx = tid & 15;   // n dir
  int ty = tid >> 4;   // m dir
  int row0 = blockIdx.x * BM;
  int col0 = blockIdx.y * BN;
  float acc[8][8] = {};
#pragma unroll
  for (int pass = 0; pass < 2; ++pass) {
    const float* A = pass ? A2 : A1;
    const float* Wp = W + (size_t)pass * F * N;
    for (int k0 = 0; k0 < F; k0 += BK) {
      // A tile: 128x16 = 512 float4, 2 per thread (transpose into LDS)
#pragma unroll
      for (int i = 0; i < 2; ++i) {
        int idx = tid + i * 256;
        int r = idx >> 2;   // row in tile
        int c4 = idx & 3;   // which float4 along k
        float4 v = make_float4(0.f, 0.f, 0.f, 0.f);
        int grow = row0 + r;
        if (grow < M)
          v = *reinterpret_cast<const float4*>(&A[(size_t)grow * F + k0 + c4 * 4]);
        As[c4 * 4 + 0][r] = v.x;
        As[c4 * 4 + 1][r] = v.y;
        As[c4 * 4 + 2][r] = v.z;
        As[c4 * 4 + 3][r] = v.w;
      }
      // W tile: 16x128 = 512 float4, 2 per thread
#pragma unroll
      for (int i = 0; i < 2; ++i) {
        int idx = tid + i * 256;
        int r = idx >> 5;   // k row
        int c4 = idx & 31;
        *reinterpret_cast<float4*>(&Ws[r][c4 * 4]) =
            *reinterpret_cast<const float4*>(&Wp[(size_t)(k0 + r) * N + col0 + c4 * 4]);
      }
      __syncthreads();
#pragma unroll
      for (int kk = 0; kk < BK; ++kk) {
        float4 a0 = *reinterpret_cast<const float4*>(&As[kk][ty * 8]);
        float4 a1 = *reinterpret_cast<const float4*>(&As[kk][ty * 8 + 4]);
        float4 b0 = *reinterpret_cast<const float4*>(&Ws[kk][tx * 8]);
        float4 b1 = *reinterpret_cast<const float4*>(&Ws[kk][tx * 8 + 4]);
        float a[8] = {a0.x, a0.y, a0.z, a0.w, a1.x, a1.y, a1.z, a1.w};
        float b[8] = {b0.x, b0.y, b0.z, b0.w, b1.x, b1.y, b1.z, b1.w};
#pragma unroll
        for (int i = 0; i < 8; ++i)
#pragma unroll
          for (int j = 0; j < 8; ++j) acc[i][j] = fmaf(a[i], b[j], acc[i][j]);
      }
      __syncthreads();
    }
  }
  // epilogue
  if (!FUSE_DEC) {
#pragma unroll
    for (int i = 0; i < 8; ++i) {
      int grow = row0 + ty * 8 + i;
      if (grow >= M) continue;
#pragma unroll
      for (int j4 = 0; j4 < 2; ++j4) {
        int gcol = col0 + tx * 8 + j4 * 4;
        float4 v;
        v.x = fmaxf(acc[i][j4 * 4 + 0] + bias[gcol + 0], 0.f);
        v.y = fmaxf(acc[i][j4 * 4 + 1] + bias[gcol + 1], 0.f);
        v.z = fmaxf(acc[i][j4 * 4 + 2] + bias[gcol + 2], 0.f);
        v.w = fmaxf(acc[i][j4 * 4 + 3] + bias[gcol + 3], 0.f);
        *reinterpret_cast<float4*>(&C[(size_t)grow * N + gcol]) = v;
      }
    }
  } else {
    // reduce relu(T) against dec_w[N,2] per row, atomically add into out[M,2]
#pragma unroll
    for (int i = 0; i < 8; ++i) {
      int grow = row0 + ty * 8 + i;
      float p0 = 0.f, p1 = 0.f;
      if (grow < M) {
#pragma unroll
        for (int j = 0; j < 8; ++j) {
          int gcol = col0 + tx * 8 + j;
          float v = fmaxf(acc[i][j] + bias[gcol], 0.f);
          p0 = fmaf(v, dw[gcol * 2 + 0], p0);
          p1 = fmaf(v, dw[gcol * 2 + 1], p1);
        }
      }
      // reduce across the 16 tx lanes sharing this row (masks <16 stay in group)
#pragma unroll
      for (int m = 1; m < 16; m <<= 1) {
        p0 += __shfl_xor(p0, m);
        p1 += __shfl_xor(p1, m);
      }
      if (tx == 0 && grow < M) {
        if (blockIdx.y == 0) { p0 += db[0]; p1 += db[1]; }
        atomicAdd(&out[(size_t)grow * 2 + 0], p0);
        atomicAdd(&out[(size_t)grow * 2 + 1], p1);
      }
    }
  }
}

extern "C" void kernel_launch(void* const* d_in, const int* in_sizes, int n_in,
                              void* d_out, int out_size, void* d_ws, size_t ws_size,
                              hipStream_t stream) {
  const float* x        = (const float*)d_in[0];
  const float* edge_attr= (const float*)d_in[1];
  const int*   ei       = (const int*)d_in[2];
  const float* enc_w    = (const float*)d_in[3];
  const float* enc_b    = (const float*)d_in[4];
  const float* e_w0     = (const float*)d_in[5];
  const float* e_b0     = (const float*)d_in[6];
  const float* l_w0     = (const float*)d_in[7];
  const float* l_b0     = (const float*)d_in[8];
  const float* e_w1     = (const float*)d_in[9];
  const float* e_b1     = (const float*)d_in[10];
  const float* l_w1     = (const float*)d_in[11];
  const float* l_b1     = (const float*)d_in[12];
  const float* dec_w    = (const float*)d_in[13];
  const float* dec_b    = (const float*)d_in[14];
  float* out = (float*)d_out;

  // Workspace layout (205.3 MB total):
  //   [h0: N*128][agg0: N*128][h1: N*256][deg: N]
  //   agg1 (N*256) aliases [h0|agg0] — both dead after gemm0.
  float* ws   = (float*)d_ws;
  float* h0   = ws;                                 // N*128
  float* agg0 = h0 + (size_t)N_NODES * 128;         // N*128
  float* h1   = agg0 + (size_t)N_NODES * 128;       // N*256
  float* deg  = h1 + (size_t)N_NODES * 256;         // N
  float* agg1 = ws;                                 // aliases [h0|agg0], N*256

  const int M = N_NODES;
  const int ZB = 1024;  // grid-stride zero blocks

  zero_kernel<<<ZB, 256, 0, stream>>>((float4*)deg, (long)N_NODES / 4);
  zero_kernel<<<ZB, 256, 0, stream>>>((float4*)agg0, (long)N_NODES * 128 / 4);

  encoder_kernel<<<N_NODES / 16, 256, 0, stream>>>(x, enc_w, enc_b, h0);
  deg_kernel<<<(N_EDGES + 255) / 256, 256, 0, stream>>>(ei, deg);

  // conv0: scatter + mean-scale + gemm
  scatter_mul<128><<<(N_EDGES * 32) / 256, 256, 0, stream>>>(h0, edge_attr, ei, e_w0, e_b0, agg0);
  scale_kernel<128><<<(N_NODES * 32) / 256, 256, 0, stream>>>(deg, agg0);
  gemm2_bias_relu<false><<<dim3((M + 127) / 128, 2), 256, 0, stream>>>(
      agg0, h0, l_w0, l_b0, h1, nullptr, nullptr, nullptr, M, 128, 256);

  // conv1: agg1 overwrites [h0|agg0] (dead after gemm0)
  zero_kernel<<<ZB, 256, 0, stream>>>((float4*)agg1, (long)N_NODES * 256 / 4);
  scatter_mul<256><<<(N_EDGES * 64) / 256, 256, 0, stream>>>(h1, edge_attr, ei, e_w1, e_b1, agg1);
  scale_kernel<256><<<(N_NODES * 64) / 256, 256, 0, stream>>>(deg, agg1);

  // gemm1 with fused decoder: out += relu(...)@dec_w (+dec_b once)
  zero_kernel<<<ZB, 256, 0, stream>>>((float4*)out, (long)out_size / 4);
  gemm2_bias_relu<true><<<dim3((M + 127) / 128, 4), 256, 0, stream>>>(
      agg1, h1, l_w1, l_b1, nullptr, dec_w, dec_b, out, M, 256, 512);
}

// Round 8
// 1629.092 us; speedup vs baseline: 3.8096x; 3.8096x over previous
//
#include <hip/hip_runtime.h>

#define N_NODES 100000
#define N_EDGES 1000000

// ---------------- zero: grid-stride float4 fill ----------------
__global__ __launch_bounds__(256) void zero_kernel(float4* __restrict__ p, long n4) {
  long i = (long)blockIdx.x * 256 + threadIdx.x;
  long stride = (long)gridDim.x * 256;
  float4 z = make_float4(0.f, 0.f, 0.f, 0.f);
  for (; i < n4; i += stride) p[i] = z;
}
__global__ __launch_bounds__(256) void zero_int_kernel(int* __restrict__ p, long n) {
  long i = (long)blockIdx.x * 256 + threadIdx.x;
  long stride = (long)gridDim.x * 256;
  for (; i < n; i += stride) p[i] = 0;
}

// ---------------- encoder: h0 = relu(x @ enc_w + enc_b), x[N,32] w[32,128] ----------------
__global__ __launch_bounds__(256) void encoder_kernel(
    const float* __restrict__ x, const float* __restrict__ w,
    const float* __restrict__ b, float* __restrict__ h) {
  __shared__ float ws[32 * 128];
  __shared__ float xs[16 * 32];
  __shared__ float bs[128];
  int tid = threadIdx.x;
#pragma unroll
  for (int i = 0; i < 4; ++i)
    reinterpret_cast<float4*>(ws)[tid + i * 256] =
        reinterpret_cast<const float4*>(w)[tid + i * 256];
  if (tid < 128) bs[tid] = b[tid];
  int n0 = blockIdx.x * 16;
  if (tid < 128)
    reinterpret_cast<float4*>(xs)[tid] =
        reinterpret_cast<const float4*>(x + (size_t)n0 * 32)[tid];
  __syncthreads();
  int f = tid & 127;
  int ng = tid >> 7;  // 2 groups x 8 nodes
#pragma unroll
  for (int i = 0; i < 8; ++i) {
    int nl = ng * 8 + i;
    float acc = bs[f];
#pragma unroll
    for (int k = 0; k < 32; ++k) acc = fmaf(xs[nl * 32 + k], ws[k * 128 + f], acc);
    h[(size_t)(n0 + nl) * 128 + f] = fmaxf(acc, 0.f);
  }
}

// ---------------- histogram: deg[dst]++ ----------------
__global__ __launch_bounds__(256) void hist_kernel(const int* __restrict__ ei,
                                                   int* __restrict__ deg) {
  int e = blockIdx.x * 256 + threadIdx.x;
  if (e < N_EDGES) atomicAdd(&deg[ei[N_EDGES + e]], 1);
}

// ---------------- exclusive scan of deg[N] -> row_start[N] (single block) ----------------
__global__ __launch_bounds__(1024) void scan_kernel(const int* __restrict__ deg,
                                                    int* __restrict__ row_start) {
  __shared__ int part[1024];
  int tid = threadIdx.x;
  const int CH = (N_NODES + 1023) / 1024;  // 98
  int start = tid * CH;
  int sum = 0;
  for (int i = 0; i < CH; ++i) {
    int idx = start + i;
    if (idx < N_NODES) sum += deg[idx];
  }
  part[tid] = sum;
  __syncthreads();
  // Hillis-Steele inclusive scan
  for (int off = 1; off < 1024; off <<= 1) {
    int v = (tid >= off) ? part[tid - off] : 0;
    __syncthreads();
    part[tid] += v;
    __syncthreads();
  }
  int prefix = (tid == 0) ? 0 : part[tid - 1];
  for (int i = 0; i < CH; ++i) {
    int idx = start + i;
    if (idx < N_NODES) {
      row_start[idx] = prefix;
      prefix += deg[idx];
    }
  }
}

// ---------------- fill CSR: permuted edge ids grouped by dst ----------------
__global__ __launch_bounds__(256) void fill_kernel(
    const int* __restrict__ ei, const int* __restrict__ row_start,
    int* __restrict__ cursor, int* __restrict__ csr_eidx) {
  int e = blockIdx.x * 256 + threadIdx.x;
  if (e >= N_EDGES) return;
  int d = ei[N_EDGES + e];
  int pos = atomicAdd(&cursor[d], 1);
  csr_eidx[row_start[d] + pos] = e;
}

// ---------------- CSR aggregate: agg[n,f] = (1/max(deg,1)) * sum_e h[src_e,f]*ea_e[f] ----------------
// one block of 256 threads per node; F=256: thread=feature; F=128: two edge-parities
template <int F>
__global__ __launch_bounds__(256) void aggregate_csr(
    const float* __restrict__ h, const int* __restrict__ row_start,
    const int* __restrict__ deg, const int* __restrict__ csr_eidx,
    const int* __restrict__ ei, const float2* __restrict__ ea2,
    const float* __restrict__ ew, const float* __restrict__ eb,
    float* __restrict__ agg) {
  constexpr int CH = 32;
  __shared__ int ssrc[CH];
  __shared__ float2 sattr[CH];
  __shared__ float sred[F == 128 ? 128 : 1];
  int n = blockIdx.x;
  int tid = threadIdx.x;
  int f = (F == 256) ? tid : (tid & 127);
  int par = (F == 256) ? 0 : (tid >> 7);
  float w0 = ew[f], w1 = ew[F + f], bb = eb[f];
  int rs = row_start[n];
  int dg = deg[n];
  float acc = 0.f;
  for (int j0 = 0; j0 < dg; j0 += CH) {
    int cnt = min(CH, dg - j0);
    __syncthreads();
    if (tid < cnt) {
      int eidx = csr_eidx[rs + j0 + tid];
      ssrc[tid] = ei[eidx];
      sattr[tid] = ea2[eidx];
    }
    __syncthreads();
    if (F == 256) {
      for (int j = 0; j < cnt; ++j) {
        float2 a = sattr[j];
        float eaw = fmaf(a.x, w0, fmaf(a.y, w1, bb));
        acc = fmaf(h[(size_t)ssrc[j] * F + f], eaw, acc);
      }
    } else {
      for (int j = par; j < cnt; j += 2) {
        float2 a = sattr[j];
        float eaw = fmaf(a.x, w0, fmaf(a.y, w1, bb));
        acc = fmaf(h[(size_t)ssrc[j] * F + f], eaw, acc);
      }
    }
  }
  float dinv = 1.f / fmaxf((float)dg, 1.f);
  if (F == 256) {
    agg[(size_t)n * F + f] = acc * dinv;
  } else {
    __syncthreads();
    if (par == 1) sred[f] = acc;
    __syncthreads();
    if (par == 0) agg[(size_t)n * F + f] = (acc + sred[f]) * dinv;
  }
}

// ---------------- two-operand GEMM: T = relu(A1 @ W[0:F] + A2 @ W[F:2F] + bias) ----------------
// If !FUSE_DEC: C = T  (C is [M,N])
// If FUSE_DEC:  out[m,0:2] += T[m, col0:col0+128] @ dw  (+ db once, from blockIdx.y==0)
template <bool FUSE_DEC>
__global__ __launch_bounds__(256) void gemm2_bias_relu(
    const float* __restrict__ A1, const float* __restrict__ A2,
    const float* __restrict__ W, const float* __restrict__ bias,
    float* __restrict__ C,
    const float* __restrict__ dw, const float* __restrict__ db,
    float* __restrict__ out, int M, int F, int N) {
  constexpr int BM = 128, BN = 128, BK = 16, PAD = 4;
  __shared__ float As[BK][BM + PAD];  // transposed: As[k][m]
  __shared__ float Ws[BK][BN + PAD];
  int tid = threadIdx.x;
  int tx = tid & 15;   // n dir
  int ty = tid >> 4;   // m dir
  int row0 = blockIdx.x * BM;
  int col0 = blockIdx.y * BN;
  float acc[8][8] = {};
#pragma unroll
  for (int pass = 0; pass < 2; ++pass) {
    const float* A = pass ? A2 : A1;
    const float* Wp = W + (size_t)pass * F * N;
    for (int k0 = 0; k0 < F; k0 += BK) {
#pragma unroll
      for (int i = 0; i < 2; ++i) {
        int idx = tid + i * 256;
        int r = idx >> 2;
        int c4 = idx & 3;
        float4 v = make_float4(0.f, 0.f, 0.f, 0.f);
        int grow = row0 + r;
        if (grow < M)
          v = *reinterpret_cast<const float4*>(&A[(size_t)grow * F + k0 + c4 * 4]);
        As[c4 * 4 + 0][r] = v.x;
        As[c4 * 4 + 1][r] = v.y;
        As[c4 * 4 + 2][r] = v.z;
        As[c4 * 4 + 3][r] = v.w;
      }
#pragma unroll
      for (int i = 0; i < 2; ++i) {
        int idx = tid + i * 256;
        int r = idx >> 5;
        int c4 = idx & 31;
        *reinterpret_cast<float4*>(&Ws[r][c4 * 4]) =
            *reinterpret_cast<const float4*>(&Wp[(size_t)(k0 + r) * N + col0 + c4 * 4]);
      }
      __syncthreads();
#pragma unroll
      for (int kk = 0; kk < BK; ++kk) {
        float4 a0 = *reinterpret_cast<const float4*>(&As[kk][ty * 8]);
        float4 a1 = *reinterpret_cast<const float4*>(&As[kk][ty * 8 + 4]);
        float4 b0 = *reinterpret_cast<const float4*>(&Ws[kk][tx * 8]);
        float4 b1 = *reinterpret_cast<const float4*>(&Ws[kk][tx * 8 + 4]);
        float a[8] = {a0.x, a0.y, a0.z, a0.w, a1.x, a1.y, a1.z, a1.w};
        float b[8] = {b0.x, b0.y, b0.z, b0.w, b1.x, b1.y, b1.z, b1.w};
#pragma unroll
        for (int i = 0; i < 8; ++i)
#pragma unroll
          for (int j = 0; j < 8; ++j) acc[i][j] = fmaf(a[i], b[j], acc[i][j]);
      }
      __syncthreads();
    }
  }
  if (!FUSE_DEC) {
#pragma unroll
    for (int i = 0; i < 8; ++i) {
      int grow = row0 + ty * 8 + i;
      if (grow >= M) continue;
#pragma unroll
      for (int j4 = 0; j4 < 2; ++j4) {
        int gcol = col0 + tx * 8 + j4 * 4;
        float4 v;
        v.x = fmaxf(acc[i][j4 * 4 + 0] + bias[gcol + 0], 0.f);
        v.y = fmaxf(acc[i][j4 * 4 + 1] + bias[gcol + 1], 0.f);
        v.z = fmaxf(acc[i][j4 * 4 + 2] + bias[gcol + 2], 0.f);
        v.w = fmaxf(acc[i][j4 * 4 + 3] + bias[gcol + 3], 0.f);
        *reinterpret_cast<float4*>(&C[(size_t)grow * N + gcol]) = v;
      }
    }
  } else {
#pragma unroll
    for (int i = 0; i < 8; ++i) {
      int grow = row0 + ty * 8 + i;
      float p0 = 0.f, p1 = 0.f;
      if (grow < M) {
#pragma unroll
        for (int j = 0; j < 8; ++j) {
          int gcol = col0 + tx * 8 + j;
          float v = fmaxf(acc[i][j] + bias[gcol], 0.f);
          p0 = fmaf(v, dw[gcol * 2 + 0], p0);
          p1 = fmaf(v, dw[gcol * 2 + 1], p1);
        }
      }
#pragma unroll
      for (int m = 1; m < 16; m <<= 1) {
        p0 += __shfl_xor(p0, m);
        p1 += __shfl_xor(p1, m);
      }
      if (tx == 0 && grow < M) {
        if (blockIdx.y == 0) { p0 += db[0]; p1 += db[1]; }
        atomicAdd(&out[(size_t)grow * 2 + 0], p0);
        atomicAdd(&out[(size_t)grow * 2 + 1], p1);
      }
    }
  }
}

extern "C" void kernel_launch(void* const* d_in, const int* in_sizes, int n_in,
                              void* d_out, int out_size, void* d_ws, size_t ws_size,
                              hipStream_t stream) {
  const float* x        = (const float*)d_in[0];
  const float* edge_attr= (const float*)d_in[1];
  const int*   ei       = (const int*)d_in[2];
  const float* enc_w    = (const float*)d_in[3];
  const float* enc_b    = (const float*)d_in[4];
  const float* e_w0     = (const float*)d_in[5];
  const float* e_b0     = (const float*)d_in[6];
  const float* l_w0     = (const float*)d_in[7];
  const float* l_b0     = (const float*)d_in[8];
  const float* e_w1     = (const float*)d_in[9];
  const float* e_b1     = (const float*)d_in[10];
  const float* l_w1     = (const float*)d_in[11];
  const float* l_b1     = (const float*)d_in[12];
  const float* dec_w    = (const float*)d_in[13];
  const float* dec_b    = (const float*)d_in[14];
  float* out = (float*)d_out;

  // Workspace layout (209.6 MB):
  //   floats: [h0:128N][agg0:128N][h1:256N], ints: [deg_i:N][row_s:N][csr_eidx:E]
  //   agg1 (256N floats) aliases [h0|agg0] — dead after gemm0.
  //   cursor (N ints) aliases agg0 — fill completes before aggregate<128> writes agg0.
  float* ws   = (float*)d_ws;
  float* h0   = ws;                                  // N*128
  float* agg0 = h0 + (size_t)N_NODES * 128;          // N*128
  float* h1   = agg0 + (size_t)N_NODES * 128;        // N*256
  float* agg1 = ws;                                  // aliases [h0|agg0]
  int* cursor = (int*)agg0;                          // aliases agg0 (dead until aggregate<128>)
  int* ip      = (int*)(h1 + (size_t)N_NODES * 256);
  int* deg_i   = ip;                                 // N
  int* row_s   = ip + N_NODES;                       // N
  int* csr_eidx= ip + 2 * N_NODES;                   // E
  const float2* ea2 = (const float2*)edge_attr;

  const int M = N_NODES;
  const int ZB = 1024;

  zero_int_kernel<<<ZB, 256, 0, stream>>>(deg_i, N_NODES);
  zero_int_kernel<<<ZB, 256, 0, stream>>>(cursor, N_NODES);

  encoder_kernel<<<N_NODES / 16, 256, 0, stream>>>(x, enc_w, enc_b, h0);
  hist_kernel<<<(N_EDGES + 255) / 256, 256, 0, stream>>>(ei, deg_i);
  scan_kernel<<<1, 1024, 0, stream>>>(deg_i, row_s);
  fill_kernel<<<(N_EDGES + 255) / 256, 256, 0, stream>>>(ei, row_s, cursor, csr_eidx);

  // conv0: CSR aggregate + gemm
  aggregate_csr<128><<<N_NODES, 256, 0, stream>>>(h0, row_s, deg_i, csr_eidx, ei, ea2,
                                                  e_w0, e_b0, agg0);
  gemm2_bias_relu<false><<<dim3((M + 127) / 128, 2), 256, 0, stream>>>(
      agg0, h0, l_w0, l_b0, h1, nullptr, nullptr, nullptr, M, 128, 256);

  // conv1: agg1 overwrites [h0|agg0] (dead after gemm0)
  aggregate_csr<256><<<N_NODES, 256, 0, stream>>>(h1, row_s, deg_i, csr_eidx, ei, ea2,
                                                  e_w1, e_b1, agg1);

  // gemm1 with fused decoder: out += relu(...)@dec_w (+dec_b once)
  zero_kernel<<<ZB, 256, 0, stream>>>((float4*)out, (long)out_size / 4);
  gemm2_bias_relu<true><<<dim3((M + 127) / 128, 4), 256, 0, stream>>>(
      agg1, h1, l_w1, l_b1, nullptr, dec_w, dec_b, out, M, 256, 512);
}

// Round 9
// 1159.187 us; speedup vs baseline: 5.3539x; 1.4054x over previous
//
#include <hip/hip_runtime.h>

#define N_NODES 100000
#define N_EDGES 1000000

typedef __attribute__((ext_vector_type(8))) short bf16x8;
typedef __attribute__((ext_vector_type(4))) float f32x4;

// split fp32 v into hi+lo bf16 (truncation; lo captures the residual, net err ~2^-16)
__device__ __forceinline__ void bsplit(float v, unsigned& hi, unsigned& lo) {
  unsigned u = __float_as_uint(v);
  hi = u >> 16;
  float hf = __uint_as_float(hi << 16);
  lo = __float_as_uint(v - hf) >> 16;
}

// ---------------- zero kernels ----------------
__global__ __launch_bounds__(256) void zero_kernel(float4* __restrict__ p, long n4) {
  long i = (long)blockIdx.x * 256 + threadIdx.x;
  long stride = (long)gridDim.x * 256;
  float4 z = make_float4(0.f, 0.f, 0.f, 0.f);
  for (; i < n4; i += stride) p[i] = z;
}
__global__ __launch_bounds__(256) void zero_int_kernel(int* __restrict__ p, long n) {
  long i = (long)blockIdx.x * 256 + threadIdx.x;
  long stride = (long)gridDim.x * 256;
  for (; i < n; i += stride) p[i] = 0;
}

// ---------------- encoder: h0 = relu(x @ enc_w + enc_b), x[N,32] w[32,128] ----------------
__global__ __launch_bounds__(256) void encoder_kernel(
    const float* __restrict__ x, const float* __restrict__ w,
    const float* __restrict__ b, float* __restrict__ h) {
  __shared__ float ws[32 * 128];
  __shared__ float xs[16 * 32];
  __shared__ float bs[128];
  int tid = threadIdx.x;
#pragma unroll
  for (int i = 0; i < 4; ++i)
    reinterpret_cast<float4*>(ws)[tid + i * 256] =
        reinterpret_cast<const float4*>(w)[tid + i * 256];
  if (tid < 128) bs[tid] = b[tid];
  int n0 = blockIdx.x * 16;
  if (tid < 128)
    reinterpret_cast<float4*>(xs)[tid] =
        reinterpret_cast<const float4*>(x + (size_t)n0 * 32)[tid];
  __syncthreads();
  int f = tid & 127;
  int ng = tid >> 7;
#pragma unroll
  for (int i = 0; i < 8; ++i) {
    int nl = ng * 8 + i;
    float acc = bs[f];
#pragma unroll
    for (int k = 0; k < 32; ++k) acc = fmaf(xs[nl * 32 + k], ws[k * 128 + f], acc);
    h[(size_t)(n0 + nl) * 128 + f] = fmaxf(acc, 0.f);
  }
}

// ---------------- histogram: deg[dst]++ ----------------
__global__ __launch_bounds__(256) void hist_kernel(const int* __restrict__ ei,
                                                   int* __restrict__ deg) {
  int e = blockIdx.x * 256 + threadIdx.x;
  if (e < N_EDGES) atomicAdd(&deg[ei[N_EDGES + e]], 1);
}

// ---------------- exclusive scan of deg[N] -> row_start[N] (single block) ----------------
__global__ __launch_bounds__(1024) void scan_kernel(const int* __restrict__ deg,
                                                    int* __restrict__ row_start) {
  __shared__ int part[1024];
  int tid = threadIdx.x;
  const int CH = (N_NODES + 1023) / 1024;
  int start = tid * CH;
  int sum = 0;
  for (int i = 0; i < CH; ++i) {
    int idx = start + i;
    if (idx < N_NODES) sum += deg[idx];
  }
  part[tid] = sum;
  __syncthreads();
  for (int off = 1; off < 1024; off <<= 1) {
    int v = (tid >= off) ? part[tid - off] : 0;
    __syncthreads();
    part[tid] += v;
    __syncthreads();
  }
  int prefix = (tid == 0) ? 0 : part[tid - 1];
  for (int i = 0; i < CH; ++i) {
    int idx = start + i;
    if (idx < N_NODES) {
      row_start[idx] = prefix;
      prefix += deg[idx];
    }
  }
}

// ---------------- fill CSR: permuted edge ids grouped by dst ----------------
__global__ __launch_bounds__(256) void fill_kernel(
    const int* __restrict__ ei, const int* __restrict__ row_start,
    int* __restrict__ cursor, int* __restrict__ csr_eidx) {
  int e = blockIdx.x * 256 + threadIdx.x;
  if (e >= N_EDGES) return;
  int d = ei[N_EDGES + e];
  int pos = atomicAdd(&cursor[d], 1);
  csr_eidx[row_start[d] + pos] = e;
}

// ---------------- CSR aggregate ----------------
template <int F>
__global__ __launch_bounds__(256) void aggregate_csr(
    const float* __restrict__ h, const int* __restrict__ row_start,
    const int* __restrict__ deg, const int* __restrict__ csr_eidx,
    const int* __restrict__ ei, const float2* __restrict__ ea2,
    const float* __restrict__ ew, const float* __restrict__ eb,
    float* __restrict__ agg) {
  constexpr int CH = 32;
  __shared__ int ssrc[CH];
  __shared__ float2 sattr[CH];
  __shared__ float sred[F == 128 ? 128 : 1];
  int n = blockIdx.x;
  int tid = threadIdx.x;
  int f = (F == 256) ? tid : (tid & 127);
  int par = (F == 256) ? 0 : (tid >> 7);
  float w0 = ew[f], w1 = ew[F + f], bb = eb[f];
  int rs = row_start[n];
  int dg = deg[n];
  float acc = 0.f;
  for (int j0 = 0; j0 < dg; j0 += CH) {
    int cnt = min(CH, dg - j0);
    __syncthreads();
    if (tid < cnt) {
      int eidx = csr_eidx[rs + j0 + tid];
      ssrc[tid] = ei[eidx];
      sattr[tid] = ea2[eidx];
    }
    __syncthreads();
    if (F == 256) {
      for (int j = 0; j < cnt; ++j) {
        float2 a = sattr[j];
        float eaw = fmaf(a.x, w0, fmaf(a.y, w1, bb));
        acc = fmaf(h[(size_t)ssrc[j] * F + f], eaw, acc);
      }
    } else {
      for (int j = par; j < cnt; j += 2) {
        float2 a = sattr[j];
        float eaw = fmaf(a.x, w0, fmaf(a.y, w1, bb));
        acc = fmaf(h[(size_t)ssrc[j] * F + f], eaw, acc);
      }
    }
  }
  float dinv = 1.f / fmaxf((float)dg, 1.f);
  if (F == 256) {
    agg[(size_t)n * F + f] = acc * dinv;
  } else {
    __syncthreads();
    if (par == 1) sred[f] = acc;
    __syncthreads();
    if (par == 0) agg[(size_t)n * F + f] = (acc + sred[f]) * dinv;
  }
}

// ---------------- split-bf16 MFMA GEMM ----------------
// T = relu(A1 @ W[0:F] + A2 @ W[F:2F] + bias);  !FUSE_DEC: C=T;  FUSE_DEC: out += T @ dw (+db once)
// BM=128, BN=256, BK=32, 512 threads = 8 waves (wm 0..3 x wn 0..1), wave = 32x128 output.
// Each fp32 input split to hi+lo bf16; 3 mfma per tile (hi*hi + hi*lo + lo*hi).
// LDS tiles [row][BK+8] bf16: 80B row stride keeps 16B alignment for ds_read_b128 frags.
template <bool FUSE_DEC>
__global__ __launch_bounds__(512) void gemm2_mfma(
    const float* __restrict__ A1, const float* __restrict__ A2,
    const float* __restrict__ W, const float* __restrict__ bias,
    float* __restrict__ C,
    const float* __restrict__ dw, const float* __restrict__ db,
    float* __restrict__ out, int M, int F, int N) {
  constexpr int BM = 128, BN = 256, BK = 32, LDK = BK + 8;
  __shared__ alignas(16) unsigned short Ah[BM * LDK];
  __shared__ alignas(16) unsigned short Al[BM * LDK];
  __shared__ alignas(16) unsigned short Bh[BN * LDK];
  __shared__ alignas(16) unsigned short Bl[BN * LDK];
  int tid = threadIdx.x;
  int wid = tid >> 6, lane = tid & 63;
  int wm = wid >> 1, wn = wid & 1;     // 4 x 2 waves
  int lg = lane >> 4, lr = lane & 15;  // lane-group (k/row group), lane-row
  int row0 = blockIdx.y * BM;          // grid.y = m-blocks
  int col0 = blockIdx.x * BN;          // grid.x = n-blocks
  f32x4 acc[2][8] = {};                // [m][n] 16x16 tiles

  for (int pass = 0; pass < 2; ++pass) {
    const float* A = pass ? A2 : A1;
    const float* Wp = W + (size_t)pass * F * N;
    for (int k0 = 0; k0 < F; k0 += BK) {
      __syncthreads();  // previous step's frags consumed
      // ---- stage A: 128x32 fp32 -> hi/lo bf16, [row][k] ----
#pragma unroll
      for (int i = 0; i < 2; ++i) {
        int id = tid + i * 512;          // 1024 float4
        int r = id >> 3, kq = id & 7;
        float4 v = make_float4(0.f, 0.f, 0.f, 0.f);
        int gr = row0 + r;
        if (gr < M) v = *reinterpret_cast<const float4*>(&A[(size_t)gr * F + k0 + kq * 4]);
        unsigned h0, l0, h1, l1, h2, l2, h3, l3;
        bsplit(v.x, h0, l0); bsplit(v.y, h1, l1);
        bsplit(v.z, h2, l2); bsplit(v.w, h3, l3);
        unsigned long long hp = (unsigned long long)h0 | ((unsigned long long)h1 << 16) |
                                ((unsigned long long)h2 << 32) | ((unsigned long long)h3 << 48);
        unsigned long long lp = (unsigned long long)l0 | ((unsigned long long)l1 << 16) |
                                ((unsigned long long)l2 << 32) | ((unsigned long long)l3 << 48);
        *reinterpret_cast<unsigned long long*>(&Ah[r * LDK + kq * 4]) = hp;
        *reinterpret_cast<unsigned long long*>(&Al[r * LDK + kq * 4]) = lp;
      }
      // ---- stage W: 32x256 fp32 -> hi/lo bf16 TRANSPOSED [col][k] (column-scalar loads, coalesced) ----
#pragma unroll
      for (int i = 0; i < 4; ++i) {
        int id = tid + i * 512;          // 2048 tasks: col(256) x kq(8)
        int c = id & 255, kq = id >> 8;
        unsigned h0, l0, h1, l1, h2, l2, h3, l3;
        float w0 = Wp[(size_t)(k0 + kq * 4 + 0) * N + col0 + c];
        float w1 = Wp[(size_t)(k0 + kq * 4 + 1) * N + col0 + c];
        float w2 = Wp[(size_t)(k0 + kq * 4 + 2) * N + col0 + c];
        float w3 = Wp[(size_t)(k0 + kq * 4 + 3) * N + col0 + c];
        bsplit(w0, h0, l0); bsplit(w1, h1, l1);
        bsplit(w2, h2, l2); bsplit(w3, h3, l3);
        unsigned long long hp = (unsigned long long)h0 | ((unsigned long long)h1 << 16) |
                                ((unsigned long long)h2 << 32) | ((unsigned long long)h3 << 48);
        unsigned long long lp = (unsigned long long)l0 | ((unsigned long long)l1 << 16) |
                                ((unsigned long long)l2 << 32) | ((unsigned long long)l3 << 48);
        *reinterpret_cast<unsigned long long*>(&Bh[c * LDK + kq * 4]) = hp;
        *reinterpret_cast<unsigned long long*>(&Bl[c * LDK + kq * 4]) = lp;
      }
      __syncthreads();
      // ---- compute: frag A lane holds row=lr, k=lg*8+t; frag B lane holds col=lr, k=lg*8+t ----
      bf16x8 ah[2], al[2];
#pragma unroll
      for (int m = 0; m < 2; ++m) {
        int rr = wm * 32 + m * 16 + lr;
        ah[m] = *reinterpret_cast<const bf16x8*>(&Ah[rr * LDK + lg * 8]);
        al[m] = *reinterpret_cast<const bf16x8*>(&Al[rr * LDK + lg * 8]);
      }
#pragma unroll
      for (int n = 0; n < 8; ++n) {
        int cc = wn * 128 + n * 16 + lr;
        bf16x8 bh = *reinterpret_cast<const bf16x8*>(&Bh[cc * LDK + lg * 8]);
        bf16x8 bl = *reinterpret_cast<const bf16x8*>(&Bl[cc * LDK + lg * 8]);
#pragma unroll
        for (int m = 0; m < 2; ++m) {
          acc[m][n] = __builtin_amdgcn_mfma_f32_16x16x32_bf16(ah[m], bh, acc[m][n], 0, 0, 0);
          acc[m][n] = __builtin_amdgcn_mfma_f32_16x16x32_bf16(ah[m], bl, acc[m][n], 0, 0, 0);
          acc[m][n] = __builtin_amdgcn_mfma_f32_16x16x32_bf16(al[m], bh, acc[m][n], 0, 0, 0);
        }
      }
    }
  }
  // ---- epilogue: D layout col=lr, row = lg*4 + reg ----
  if (!FUSE_DEC) {
#pragma unroll
    for (int m = 0; m < 2; ++m) {
#pragma unroll
      for (int r = 0; r < 4; ++r) {
        int grow = row0 + wm * 32 + m * 16 + lg * 4 + r;
        if (grow >= M) continue;
#pragma unroll
        for (int n = 0; n < 8; ++n) {
          int gcol = col0 + wn * 128 + n * 16 + lr;
          C[(size_t)grow * N + gcol] = fmaxf(acc[m][n][r] + bias[gcol], 0.f);
        }
      }
    }
  } else {
#pragma unroll
    for (int m = 0; m < 2; ++m) {
#pragma unroll
      for (int r = 0; r < 4; ++r) {
        int grow = row0 + wm * 32 + m * 16 + lg * 4 + r;
        float p0 = 0.f, p1 = 0.f;
#pragma unroll
        for (int n = 0; n < 8; ++n) {
          int gcol = col0 + wn * 128 + n * 16 + lr;
          float v = fmaxf(acc[m][n][r] + bias[gcol], 0.f);
          p0 = fmaf(v, dw[gcol * 2 + 0], p0);
          p1 = fmaf(v, dw[gcol * 2 + 1], p1);
        }
#pragma unroll
        for (int s = 1; s < 16; s <<= 1) {
          p0 += __shfl_xor(p0, s);
          p1 += __shfl_xor(p1, s);
        }
        if (lr == 0 && grow < M) {
          if (wn == 0 && blockIdx.x == 0) { p0 += db[0]; p1 += db[1]; }  // db once per row
          atomicAdd(&out[(size_t)grow * 2 + 0], p0);
          atomicAdd(&out[(size_t)grow * 2 + 1], p1);
        }
      }
    }
  }
}

extern "C" void kernel_launch(void* const* d_in, const int* in_sizes, int n_in,
                              void* d_out, int out_size, void* d_ws, size_t ws_size,
                              hipStream_t stream) {
  const float* x        = (const float*)d_in[0];
  const float* edge_attr= (const float*)d_in[1];
  const int*   ei       = (const int*)d_in[2];
  const float* enc_w    = (const float*)d_in[3];
  const float* enc_b    = (const float*)d_in[4];
  const float* e_w0     = (const float*)d_in[5];
  const float* e_b0     = (const float*)d_in[6];
  const float* l_w0     = (const float*)d_in[7];
  const float* l_b0     = (const float*)d_in[8];
  const float* e_w1     = (const float*)d_in[9];
  const float* e_b1     = (const float*)d_in[10];
  const float* l_w1     = (const float*)d_in[11];
  const float* l_b1     = (const float*)d_in[12];
  const float* dec_w    = (const float*)d_in[13];
  const float* dec_b    = (const float*)d_in[14];
  float* out = (float*)d_out;

  // Workspace layout (209.6 MB) — unchanged from round 8:
  float* ws   = (float*)d_ws;
  float* h0   = ws;                                  // N*128
  float* agg0 = h0 + (size_t)N_NODES * 128;          // N*128
  float* h1   = agg0 + (size_t)N_NODES * 128;        // N*256
  float* agg1 = ws;                                  // aliases [h0|agg0] (dead after gemm0)
  int* cursor = (int*)agg0;                          // aliases agg0 (dead until aggregate<128>)
  int* ip      = (int*)(h1 + (size_t)N_NODES * 256);
  int* deg_i   = ip;                                 // N
  int* row_s   = ip + N_NODES;                       // N
  int* csr_eidx= ip + 2 * N_NODES;                   // E
  const float2* ea2 = (const float2*)edge_attr;

  const int M = N_NODES;
  const int ZB = 1024;

  zero_int_kernel<<<ZB, 256, 0, stream>>>(deg_i, N_NODES);
  zero_int_kernel<<<ZB, 256, 0, stream>>>(cursor, N_NODES);

  encoder_kernel<<<N_NODES / 16, 256, 0, stream>>>(x, enc_w, enc_b, h0);
  hist_kernel<<<(N_EDGES + 255) / 256, 256, 0, stream>>>(ei, deg_i);
  scan_kernel<<<1, 1024, 0, stream>>>(deg_i, row_s);
  fill_kernel<<<(N_EDGES + 255) / 256, 256, 0, stream>>>(ei, row_s, cursor, csr_eidx);

  // conv0: CSR aggregate + mfma gemm (N=256 -> 1 col-block)
  aggregate_csr<128><<<N_NODES, 256, 0, stream>>>(h0, row_s, deg_i, csr_eidx, ei, ea2,
                                                  e_w0, e_b0, agg0);
  gemm2_mfma<false><<<dim3(1, (M + 127) / 128), 512, 0, stream>>>(
      agg0, h0, l_w0, l_b0, h1, nullptr, nullptr, nullptr, M, 128, 256);

  // conv1
  aggregate_csr<256><<<N_NODES, 256, 0, stream>>>(h1, row_s, deg_i, csr_eidx, ei, ea2,
                                                  e_w1, e_b1, agg1);

  // gemm1 + fused decoder (N=512 -> 2 col-blocks)
  zero_kernel<<<ZB, 256, 0, stream>>>((float4*)out, (long)out_size / 4);
  gemm2_mfma<true><<<dim3(2, (M + 127) / 128), 512, 0, stream>>>(
      agg1, h1, l_w1, l_b1, nullptr, dec_w, dec_b, out, M, 256, 512);
}